// Round 12
// baseline (267.350 us; speedup 1.0000x reference)
//
#include <hip/hip_runtime.h>
#include <math.h>

#define NCH 48
#define NB 16
#define PLANE 16384
#define NPLANES 768

// d_ws float layout
#define WS_PSUM  0
#define WS_PSQ   768
#define WS_SCALE 1536
#define WS_SHIFT 1584
#define WS_TAB   1632   // [src 4][tgt 4][6 coefs]
#define WS_CONST 1728   // [4]

typedef _Float16 h2 __attribute__((ext_vector_type(2)));

// ---------------- stage A: per-plane partial sums ----------------
__global__ __launch_bounds__(256) void stats_kernel(const float* __restrict__ x,
                                                    float* __restrict__ ws) {
  int p = blockIdx.x;
  int t = threadIdx.x;
  const float4* x4 = (const float4*)x + (size_t)p * 4096;
  float s = 0.f, q = 0.f;
  #pragma unroll
  for (int k = 0; k < 16; ++k) {
    float4 v = x4[k * 256 + t];
    s += v.x + v.y + v.z + v.w;
    q += v.x * v.x + v.y * v.y + v.z * v.z + v.w * v.w;
  }
  #pragma unroll
  for (int off = 32; off > 0; off >>= 1) {
    s += __shfl_xor(s, off, 64);
    q += __shfl_xor(q, off, 64);
  }
  __shared__ float red[8];
  int wid = t >> 6, lane = t & 63;
  if (lane == 0) { red[wid] = s; red[4 + wid] = q; }
  __syncthreads();
  if (t == 0) {
    ws[WS_PSUM + p] = red[0] + red[1] + red[2] + red[3];
    ws[WS_PSQ  + p] = red[4] + red[5] + red[6] + red[7];
  }
}

// ---------------- stage B: BN params + merged weight table ----------------
__global__ void prep_kernel(const float* __restrict__ gamma, const float* __restrict__ beta,
                            const float* __restrict__ alphas, float* __restrict__ ws) {
  int t = threadIdx.x;
  if (t < NCH) {
    float s = 0.f, q = 0.f;
    for (int b = 0; b < NB; ++b) {
      s += ws[WS_PSUM + b * NCH + t];
      q += ws[WS_PSQ  + b * NCH + t];
    }
    const float inv = 1.0f / ((float)NB * PLANE);
    float mean = s * inv;
    float var  = q * inv - mean * mean;
    float sc = gamma[t] * rsqrtf(var + 1e-5f);
    ws[WS_SCALE + t] = sc;
    ws[WS_SHIFT + t] = beta[t] - mean * sc;
  }
  if (t == 0) {
    float w[14][7];
    for (int r = 0; r < 14; ++r) {
      float m = -1e30f;
      for (int k = 0; k < 7; ++k) m = fmaxf(m, alphas[r * 7 + k]);
      float sum = 0.f;
      for (int k = 0; k < 7; ++k) { float e = expf(alphas[r * 7 + k] - m); w[r][k] = e; sum += e; }
      float is = 1.0f / sum;
      for (int k = 0; k < 7; ++k) w[r][k] *= is;
    }
    for (int i = 0; i < 96; ++i) ws[WS_TAB + i] = 0.f;
    for (int i = 0; i < 4;  ++i) ws[WS_CONST + i] = 0.f;
    const int map[14][2] = {
      {0,0},{0,0},
      {0,1},{0,1},{1,1},
      {0,2},{0,2},{1,2},{2,2},
      {0,3},{0,3},{1,3},{2,3},{3,3}
    };
    for (int r = 0; r < 14; ++r) {
      int p = map[r][0], tg = map[r][1];
      float* cf = ws + WS_TAB + (p * 4 + tg) * 6;
      cf[0] += w[r][0] - w[r][2];       // identity
      cf[1] += w[r][1] * (1.0f / 9.0f); // blur (/9 folded)
      cf[2] += w[r][3];                 // fliplr
      cf[3] += w[r][4];                 // flipud
      cf[4] += w[r][5];                 // roll(+4,+4)
      cf[5] += w[r][6];                 // rot90
      ws[WS_CONST + tg] += w[r][2];     // constant w2
    }
  }
}

// ---------------- main fused kernel ----------------
// fp16 LDS planes, SPLIT-WORD layout (R11 post-mortem: old adjacent-word
// quads put both b32 reads on even banks only -> 4-way conflict on every
// row read). Row i = 64 h2: [word0 of quads 0..31][word1 of quads 0..31],
// quad index XOR-swizzled per row. Both words of a quad read with b32 at
// bank q^(i&31) -> all 32 banks across a wave (2 lanes/bank = free).

__device__ __forceinline__ float ldshw(const h2* L, int i, int j) {
  int q = ((j >> 2) & 31) ^ (i & 31);
  h2 p = L[(i << 6) + ((j & 2) << 4) + q];
  return (j & 1) ? (float)p.y : (float)p.x;
}

#define RDQ(L, I, B, M) {                                                      \
  int q_ = (B) ^ ((I) & 31);                                                   \
  h2 p0_ = (L)[((I) << 6) + q_];                                               \
  h2 p1_ = (L)[((I) << 6) + 32 + q_];                                          \
  M.x = (float)p0_.x; M.y = (float)p0_.y;                                      \
  M.z = (float)p1_.x; M.w = (float)p1_.y; }

#define WRQ(L, I, B, V) {                                                      \
  int q_ = (B) ^ ((I) & 31);                                                   \
  h2 p0_, p1_;                                                                 \
  p0_.x = (_Float16)V.x; p0_.y = (_Float16)V.y;                                \
  p1_.x = (_Float16)V.z; p1_.y = (_Float16)V.w;                                \
  (L)[((I) << 6) + q_] = p0_;                                                  \
  (L)[((I) << 6) + 32 + q_] = p1_; }

#define HROW(h, m, lo, hi)                                                     \
  h.x = lo + m.x + m.y; h.y = m.x + m.y + m.z;                                 \
  h.z = m.y + m.z + m.w; h.w = m.z + m.w + hi;

// ACC hooks: ACC(row, comp, opIdx, value)
#define FMA4A(ACC, R, OP, M) ACC(R,x,OP,M.x) ACC(R,y,OP,M.y) ACC(R,z,OP,M.z) ACC(R,w,OP,M.w)
#define FLIPLA(ACC, R, M)    ACC(R,x,2,M.w) ACC(R,y,2,M.z) ACC(R,z,2,M.y) ACC(R,w,2,M.x)
#define BLUR4A(ACC, R, Ah, Bh, Ch)                                             \
  ACC(R,x,1,(Ah.x+Bh.x+Ch.x)) ACC(R,y,1,(Ah.y+Bh.y+Ch.y))                      \
  ACC(R,z,1,(Ah.z+Bh.z+Ch.z)) ACC(R,w,1,(Ah.w+Bh.w+Ch.w))

#define GATHER(L, OI, TYC, ACC) {                                              \
  float4 m, hA, hB, hC; float lo, hi; int ri;                                  \
  ri = ((OI) == 0) ? 1 : (OI) - 1;                                             \
  RDQ(L, ri, tx, m) lo = ldshw(L, ri, cLo); hi = ldshw(L, ri, cHi);            \
  HROW(hA, m, lo, hi)                                                          \
  RDQ(L, (OI), tx, m) lo = ldshw(L, (OI), cLo); hi = ldshw(L, (OI), cHi);      \
  FMA4A(ACC, 0, 0, m)                                                          \
  HROW(hB, m, lo, hi)                                                          \
  RDQ(L, (OI)+1, tx, m) lo = ldshw(L, (OI)+1, cLo); hi = ldshw(L, (OI)+1, cHi);\
  FMA4A(ACC, 1, 0, m)                                                          \
  HROW(hC, m, lo, hi)                                                          \
  BLUR4A(ACC, 0, hA, hB, hC)                                                   \
  RDQ(L, (OI)+2, tx, m) lo = ldshw(L, (OI)+2, cLo); hi = ldshw(L, (OI)+2, cHi);\
  FMA4A(ACC, 2, 0, m)                                                          \
  HROW(hA, m, lo, hi)                                                          \
  BLUR4A(ACC, 1, hB, hC, hA)                                                   \
  RDQ(L, (OI)+3, tx, m) lo = ldshw(L, (OI)+3, cLo); hi = ldshw(L, (OI)+3, cHi);\
  FMA4A(ACC, 3, 0, m)                                                          \
  HROW(hB, m, lo, hi)                                                          \
  BLUR4A(ACC, 2, hC, hA, hB)                                                   \
  ri = ((OI) == 124) ? 126 : (OI) + 4;                                         \
  RDQ(L, ri, tx, m) lo = ldshw(L, ri, cLo); hi = ldshw(L, ri, cHi);            \
  HROW(hC, m, lo, hi)                                                          \
  BLUR4A(ACC, 3, hA, hB, hC)                                                   \
  /* fliplr */                                                                 \
  RDQ(L, (OI),   31 - tx, m) FLIPLA(ACC, 0, m)                                 \
  RDQ(L, (OI)+1, 31 - tx, m) FLIPLA(ACC, 1, m)                                 \
  RDQ(L, (OI)+2, 31 - tx, m) FLIPLA(ACC, 2, m)                                 \
  RDQ(L, (OI)+3, 31 - tx, m) FLIPLA(ACC, 3, m)                                 \
  /* flipud */                                                                 \
  RDQ(L, 127 - (OI), tx, m) FMA4A(ACC, 0, 3, m)                                \
  RDQ(L, 126 - (OI), tx, m) FMA4A(ACC, 1, 3, m)                                \
  RDQ(L, 125 - (OI), tx, m) FMA4A(ACC, 2, 3, m)                                \
  RDQ(L, 124 - (OI), tx, m) FMA4A(ACC, 3, 3, m)                                \
  /* roll(+4,+4) */                                                            \
  RDQ(L, ((OI) - 4) & 127, rc, m) FMA4A(ACC, 0, 4, m)                          \
  RDQ(L, ((OI) - 3) & 127, rc, m) FMA4A(ACC, 1, 4, m)                          \
  RDQ(L, ((OI) - 2) & 127, rc, m) FMA4A(ACC, 2, 4, m)                          \
  RDQ(L, ((OI) - 1) & 127, rc, m) FMA4A(ACC, 3, 4, m)                          \
  /* rot90 k=1: out[i][j] = src[j][127-i] */                                   \
  RDQ(L, oj,     31 - (TYC), m)                                                \
  ACC(0,x,5,m.w) ACC(1,x,5,m.z) ACC(2,x,5,m.y) ACC(3,x,5,m.x)                  \
  RDQ(L, oj + 1, 31 - (TYC), m)                                                \
  ACC(0,y,5,m.w) ACC(1,y,5,m.z) ACC(2,y,5,m.y) ACC(3,y,5,m.x)                  \
  RDQ(L, oj + 2, 31 - (TYC), m)                                                \
  ACC(0,z,5,m.w) ACC(1,z,5,m.z) ACC(2,z,5,m.y) ACC(3,z,5,m.x)                  \
  RDQ(L, oj + 3, 31 - (TYC), m)                                                \
  ACC(0,w,5,m.w) ACC(1,w,5,m.z) ACC(2,w,5,m.y) ACC(3,w,5,m.x)                  \
}

// accumulator hooks. T-only; T+p5 piggyback (per chunk A..D); p5-only.
#define ACC_T(R,Cc,OP,V)   T##R.Cc += wA##OP * (V);
#define ACC_TD(R,Cc,OP,V)  T##R.Cc += wD##OP * (V);
#define ACC_PA_A(R,Cc,OP,V) { float v_=(V); T##R.Cc += wA##OP*v_; p5A_##R.Cc += wC##OP*v_; }
#define ACC_PA_B(R,Cc,OP,V) { float v_=(V); T##R.Cc += wA##OP*v_; p5B_##R.Cc += wC##OP*v_; }
#define ACC_PA_C(R,Cc,OP,V) { float v_=(V); T##R.Cc += wA##OP*v_; p5C_##R.Cc += wC##OP*v_; }
#define ACC_PA_D(R,Cc,OP,V) { float v_=(V); T##R.Cc += wA##OP*v_; p5D_##R.Cc += wC##OP*v_; }
#define ACC_PB_A(R,Cc,OP,V) { float v_=(V); T##R.Cc += wD##OP*v_; p5A_##R.Cc += wC##OP*v_; }
#define ACC_PB_B(R,Cc,OP,V) { float v_=(V); T##R.Cc += wD##OP*v_; p5B_##R.Cc += wC##OP*v_; }
#define ACC_PB_C(R,Cc,OP,V) { float v_=(V); T##R.Cc += wD##OP*v_; p5C_##R.Cc += wC##OP*v_; }
#define ACC_PB_D(R,Cc,OP,V) { float v_=(V); T##R.Cc += wD##OP*v_; p5D_##R.Cc += wC##OP*v_; }
#define ACC_D_A(R,Cc,OP,V) p5A_##R.Cc += wA##OP * (V);
#define ACC_D_B(R,Cc,OP,V) p5B_##R.Cc += wA##OP * (V);
#define ACC_D_C(R,Cc,OP,V) p5C_##R.Cc += wA##OP * (V);
#define ACC_D_D(R,Cc,OP,V) p5D_##R.Cc += wA##OP * (V);

#define LDCFS(PRE, P, TG) {                                                    \
  const float* cfp_ = wsf + WS_TAB + ((P) * 4 + (TG)) * 6;                     \
  PRE##0 = cfp_[0]; PRE##1 = cfp_[1]; PRE##2 = cfp_[2];                        \
  PRE##3 = cfp_[3]; PRE##4 = cfp_[4]; PRE##5 = cfp_[5]; }

#define SETT(VV) { T0 = VV; T1 = VV; T2 = VV; T3 = VV; }

#define STAGE_BN(L, OI) {                                                      \
  float4 v;                                                                    \
  v = x4[((OI)+0)*32 + tx]; v.x = v.x*sc+sh; v.y = v.y*sc+sh; v.z = v.z*sc+sh; \
  v.w = v.w*sc+sh; WRQ(L, (OI)+0, tx, v)                                       \
  v = x4[((OI)+1)*32 + tx]; v.x = v.x*sc+sh; v.y = v.y*sc+sh; v.z = v.z*sc+sh; \
  v.w = v.w*sc+sh; WRQ(L, (OI)+1, tx, v)                                       \
  v = x4[((OI)+2)*32 + tx]; v.x = v.x*sc+sh; v.y = v.y*sc+sh; v.z = v.z*sc+sh; \
  v.w = v.w*sc+sh; WRQ(L, (OI)+2, tx, v)                                       \
  v = x4[((OI)+3)*32 + tx]; v.x = v.x*sc+sh; v.y = v.y*sc+sh; v.z = v.z*sc+sh; \
  v.w = v.w*sc+sh; WRQ(L, (OI)+3, tx, v) }

#define STAGE_OUT(L, TG, OI) {                                                 \
  float4 v;                                                                    \
  v = out4[(pbase + (TG)*NCH)*4096 + ((OI)+0)*32 + tx]; WRQ(L, (OI)+0, tx, v)  \
  v = out4[(pbase + (TG)*NCH)*4096 + ((OI)+1)*32 + tx]; WRQ(L, (OI)+1, tx, v)  \
  v = out4[(pbase + (TG)*NCH)*4096 + ((OI)+2)*32 + tx]; WRQ(L, (OI)+2, tx, v)  \
  v = out4[(pbase + (TG)*NCH)*4096 + ((OI)+3)*32 + tx]; WRQ(L, (OI)+3, tx, v) }

#define WRITET(TG, OI) {                                                       \
  out4[(pbase + (TG)*NCH)*4096 + ((OI)+0)*32 + tx] = T0;                       \
  out4[(pbase + (TG)*NCH)*4096 + ((OI)+1)*32 + tx] = T1;                       \
  out4[(pbase + (TG)*NCH)*4096 + ((OI)+2)*32 + tx] = T2;                       \
  out4[(pbase + (TG)*NCH)*4096 + ((OI)+3)*32 + tx] = T3; }

#define LOADT(TG, OI) {                                                        \
  T0 = out4[(pbase + (TG)*NCH)*4096 + ((OI)+0)*32 + tx];                       \
  T1 = out4[(pbase + (TG)*NCH)*4096 + ((OI)+1)*32 + tx];                       \
  T2 = out4[(pbase + (TG)*NCH)*4096 + ((OI)+2)*32 + tx];                       \
  T3 = out4[(pbase + (TG)*NCH)*4096 + ((OI)+3)*32 + tx]; }

#define STASHT(L, OI) {                                                        \
  WRQ(L, (OI)+0, tx, T0) WRQ(L, (OI)+1, tx, T1)                                \
  WRQ(L, (OI)+2, tx, T2) WRQ(L, (OI)+3, tx, T3) }

#define WRITEP(P, TG, OI) {                                                    \
  out4[(pbase + (TG)*NCH)*4096 + ((OI)+0)*32 + tx] = P##_0;                    \
  out4[(pbase + (TG)*NCH)*4096 + ((OI)+1)*32 + tx] = P##_1;                    \
  out4[(pbase + (TG)*NCH)*4096 + ((OI)+2)*32 + tx] = P##_2;                    \
  out4[(pbase + (TG)*NCH)*4096 + ((OI)+3)*32 + tx] = P##_3; }

#define INITP(P, VV) { P##_0 = VV; P##_1 = VV; P##_2 = VV; P##_3 = VV; }

// launch_bounds(256,1): the config that granted 180 VGPR (R10). Demand here
// ~120 (p5 64 + T 16 + temps). 64 KB LDS -> 2 blocks/CU.
__global__ __launch_bounds__(256, 1)
void main_kernel(const float* __restrict__ x,
                 const float* __restrict__ wsf, float* out)
{
  __shared__ h2 lds[2 * 8192];            // 64 KB
  h2* h0 = lds;
  h2* h1 = lds + 8192;
  int bx = blockIdx.x;
  int b = bx / NCH, c = bx % NCH;
  int tid = threadIdx.x;
  int ty = tid >> 5, tx = tid & 31;       // ty in 0..7
  int oj = tx << 2;
  int cLo = (tx == 0)  ? 1   : oj - 1;
  int cHi = (tx == 31) ? 126 : oj + 4;
  int rc  = (tx + 31) & 31;
  float4* out4 = (float4*)out;
  const size_t pbase = (size_t)b * 192 + c;
  const float4* x4 = (const float4*)x + (size_t)bx * 4096;
  float sc = wsf[WS_SCALE + c], sh = wsf[WS_SHIFT + c];

  const int oiA = ty << 2,        tyA = ty;
  const int oiB = (ty + 8) << 2,  tyB = ty + 8;
  const int oiC = (ty + 16) << 2, tyC2 = ty + 16;
  const int oiD = (ty + 24) << 2, tyD = ty + 24;

  float4 T0, T1, T2, T3;
  float wA0, wA1, wA2, wA3, wA4, wA5;
  float wC0, wC1, wC2, wC3, wC4, wC5;
  float wD0, wD1, wD2, wD3, wD4, wD5;

  // persistent s5 accumulator: 4 chunks x 4 rows = 64 VGPR
  float4 p5A_0, p5A_1, p5A_2, p5A_3;
  float4 p5B_0, p5B_1, p5B_2, p5B_3;
  float4 p5C_0, p5C_1, p5C_2, p5C_3;
  float4 p5D_0, p5D_1, p5D_2, p5D_3;
  {
    float c3_ = wsf[WS_CONST + 3];
    float4 v3; v3.x = c3_; v3.y = c3_; v3.z = c3_; v3.w = c3_;
    INITP(p5A, v3) INITP(p5B, v3) INITP(p5C, v3) INITP(p5D, v3)
  }

  // stage s -> b0
  STAGE_BN(h0, oiA) STAGE_BN(h0, oiB) STAGE_BN(h0, oiC) STAGE_BN(h0, oiD)
  __syncthreads();

  // ---- pass1: s -> s2 (T), piggy p5 += L(0,3)[s]; stash s2 -> b1 ----
  LDCFS(wA, 0, 0) LDCFS(wC, 0, 3)
  {
    float c0_ = wsf[WS_CONST + 0];
    float4 v0; v0.x = c0_; v0.y = c0_; v0.z = c0_; v0.w = c0_;
    SETT(v0) GATHER(h0, oiA, tyA,  ACC_PA_A) WRITET(0, oiA) STASHT(h1, oiA)
    SETT(v0) GATHER(h0, oiB, tyB,  ACC_PA_B) WRITET(0, oiB) STASHT(h1, oiB)
    SETT(v0) GATHER(h0, oiC, tyC2, ACC_PA_C) WRITET(0, oiC) STASHT(h1, oiC)
    SETT(v0) GATHER(h0, oiD, tyD,  ACC_PA_D) WRITET(0, oiD) STASHT(h1, oiD)
  }
  __syncthreads();

  // ---- pass2: s3 = c1 + L(0,1)[s] + L(1,1)[s2]; piggy p5 += L(1,3)[s2] ----
  LDCFS(wA, 0, 1) LDCFS(wD, 1, 1) LDCFS(wC, 1, 3)
  {
    float c1_ = wsf[WS_CONST + 1];
    float4 v1; v1.x = c1_; v1.y = c1_; v1.z = c1_; v1.w = c1_;
    SETT(v1) GATHER(h0, oiA, tyA,  ACC_T) GATHER(h1, oiA, tyA,  ACC_PB_A) WRITET(1, oiA)
    SETT(v1) GATHER(h0, oiB, tyB,  ACC_T) GATHER(h1, oiB, tyB,  ACC_PB_B) WRITET(1, oiB)
    SETT(v1) GATHER(h0, oiC, tyC2, ACC_T) GATHER(h1, oiC, tyC2, ACC_PB_C) WRITET(1, oiC)
    SETT(v1) GATHER(h0, oiD, tyD,  ACC_T) GATHER(h1, oiD, tyD,  ACC_PB_D) WRITET(1, oiD)
  }
  // no LDS writes since pass1's sync -> no barrier needed before pass3a

  // ---- pass3a: partial s4 = c2 + L(0,2)[s] + L(1,2)[s2] (write to out) ----
  LDCFS(wA, 0, 2) LDCFS(wD, 1, 2)
  {
    float c2_ = wsf[WS_CONST + 2];
    float4 v2; v2.x = c2_; v2.y = c2_; v2.z = c2_; v2.w = c2_;
    SETT(v2) GATHER(h0, oiA, tyA,  ACC_T) GATHER(h1, oiA, tyA,  ACC_TD) WRITET(2, oiA)
    SETT(v2) GATHER(h0, oiB, tyB,  ACC_T) GATHER(h1, oiB, tyB,  ACC_TD) WRITET(2, oiB)
    SETT(v2) GATHER(h0, oiC, tyC2, ACC_T) GATHER(h1, oiC, tyC2, ACC_TD) WRITET(2, oiC)
    SETT(v2) GATHER(h0, oiD, tyD,  ACC_T) GATHER(h1, oiD, tyD,  ACC_TD) WRITET(2, oiD)
  }
  __syncthreads();                        // s and s2 reads complete

  // restage s3 -> b0 (same-thread global re-read, L2-hot)
  STAGE_OUT(h0, 1, oiA) STAGE_OUT(h0, 1, oiB)
  STAGE_OUT(h0, 1, oiC) STAGE_OUT(h0, 1, oiD)
  __syncthreads();

  // ---- pass3b: s4 final += L(2,2)[s3]; piggy p5 += L(2,3)[s3];
  //      stash s4 -> b1 (b1's s2 reads all completed before last sync) ----
  LDCFS(wA, 2, 2) LDCFS(wC, 2, 3)
  LOADT(2, oiA) GATHER(h0, oiA, tyA,  ACC_PA_A) WRITET(2, oiA) STASHT(h1, oiA)
  LOADT(2, oiB) GATHER(h0, oiB, tyB,  ACC_PA_B) WRITET(2, oiB) STASHT(h1, oiB)
  LOADT(2, oiC) GATHER(h0, oiC, tyC2, ACC_PA_C) WRITET(2, oiC) STASHT(h1, oiC)
  LOADT(2, oiD) GATHER(h0, oiD, tyD,  ACC_PA_D) WRITET(2, oiD) STASHT(h1, oiD)
  __syncthreads();                        // s4 fully staged in b1

  // ---- pass4: s5 = p5 + L(3,3)[s4] ----
  LDCFS(wA, 3, 3)
  GATHER(h1, oiA, tyA,  ACC_D_A) WRITEP(p5A, 3, oiA)
  GATHER(h1, oiB, tyB,  ACC_D_B) WRITEP(p5B, 3, oiB)
  GATHER(h1, oiC, tyC2, ACC_D_C) WRITEP(p5C, 3, oiC)
  GATHER(h1, oiD, tyD,  ACC_D_D) WRITEP(p5D, 3, oiD)
}

extern "C" void kernel_launch(void* const* d_in, const int* in_sizes, int n_in,
                              void* d_out, int out_size, void* d_ws, size_t ws_size,
                              hipStream_t stream) {
  (void)in_sizes; (void)n_in; (void)out_size; (void)ws_size;
  const float* x     = (const float*)d_in[0];
  const float* gamma = (const float*)d_in[1];
  const float* beta  = (const float*)d_in[2];
  const float* a_red = (const float*)d_in[4];   // reference uses alphas_reduce
  float* ws  = (float*)d_ws;
  float* out = (float*)d_out;

  stats_kernel<<<NPLANES, 256, 0, stream>>>(x, ws);
  prep_kernel<<<1, 64, 0, stream>>>(gamma, beta, a_red, ws);
  main_kernel<<<NPLANES, 256, 0, stream>>>(x, ws, out);
}

// Round 13
// 116.560 us; speedup vs baseline: 2.2937x; 2.2937x over previous
//
#include <hip/hip_runtime.h>
#include <math.h>

#define NCH 48
#define NB 16
#define PLANE 16384
#define NPLANES 768

// d_ws float layout
#define WS_PSUM  0
#define WS_PSQ   768
#define WS_SCALE 1536
#define WS_SHIFT 1584
#define WS_TAB   1632   // [src 4][tgt 4][6 coefs]
#define WS_CONST 1728   // [4]

typedef _Float16 h2 __attribute__((ext_vector_type(2)));

// ---------------- stage A: per-plane partial sums ----------------
__global__ __launch_bounds__(256) void stats_kernel(const float* __restrict__ x,
                                                    float* __restrict__ ws) {
  int p = blockIdx.x;
  int t = threadIdx.x;
  const float4* x4 = (const float4*)x + (size_t)p * 4096;
  float s = 0.f, q = 0.f;
  #pragma unroll
  for (int k = 0; k < 16; ++k) {
    float4 v = x4[k * 256 + t];
    s += v.x + v.y + v.z + v.w;
    q += v.x * v.x + v.y * v.y + v.z * v.z + v.w * v.w;
  }
  #pragma unroll
  for (int off = 32; off > 0; off >>= 1) {
    s += __shfl_xor(s, off, 64);
    q += __shfl_xor(q, off, 64);
  }
  __shared__ float red[8];
  int wid = t >> 6, lane = t & 63;
  if (lane == 0) { red[wid] = s; red[4 + wid] = q; }
  __syncthreads();
  if (t == 0) {
    ws[WS_PSUM + p] = red[0] + red[1] + red[2] + red[3];
    ws[WS_PSQ  + p] = red[4] + red[5] + red[6] + red[7];
  }
}

// ---------------- stage B: BN params + merged weight table ----------------
__global__ void prep_kernel(const float* __restrict__ gamma, const float* __restrict__ beta,
                            const float* __restrict__ alphas, float* __restrict__ ws) {
  int t = threadIdx.x;
  if (t < NCH) {
    float s = 0.f, q = 0.f;
    for (int b = 0; b < NB; ++b) {
      s += ws[WS_PSUM + b * NCH + t];
      q += ws[WS_PSQ  + b * NCH + t];
    }
    const float inv = 1.0f / ((float)NB * PLANE);
    float mean = s * inv;
    float var  = q * inv - mean * mean;
    float sc = gamma[t] * rsqrtf(var + 1e-5f);
    ws[WS_SCALE + t] = sc;
    ws[WS_SHIFT + t] = beta[t] - mean * sc;
  }
  if (t == 0) {
    float w[14][7];
    for (int r = 0; r < 14; ++r) {
      float m = -1e30f;
      for (int k = 0; k < 7; ++k) m = fmaxf(m, alphas[r * 7 + k]);
      float sum = 0.f;
      for (int k = 0; k < 7; ++k) { float e = expf(alphas[r * 7 + k] - m); w[r][k] = e; sum += e; }
      float is = 1.0f / sum;
      for (int k = 0; k < 7; ++k) w[r][k] *= is;
    }
    for (int i = 0; i < 96; ++i) ws[WS_TAB + i] = 0.f;
    for (int i = 0; i < 4;  ++i) ws[WS_CONST + i] = 0.f;
    const int map[14][2] = {
      {0,0},{0,0},
      {0,1},{0,1},{1,1},
      {0,2},{0,2},{1,2},{2,2},
      {0,3},{0,3},{1,3},{2,3},{3,3}
    };
    for (int r = 0; r < 14; ++r) {
      int p = map[r][0], tg = map[r][1];
      float* cf = ws + WS_TAB + (p * 4 + tg) * 6;
      cf[0] += w[r][0] - w[r][2];       // identity
      cf[1] += w[r][1] * (1.0f / 9.0f); // blur (/9 folded)
      cf[2] += w[r][3];                 // fliplr
      cf[3] += w[r][4];                 // flipud
      cf[4] += w[r][5];                 // roll(+4,+4)
      cf[5] += w[r][6];                 // rot90
      ws[WS_CONST + tg] += w[r][2];     // constant w2
    }
  }
}

// ---------------- main fused kernel ----------------
// fp16 LDS planes, split-word layout, XOR swizzle on (i>>2) [R12 post-mortem:
// XOR on (i&31) left rot90's stride-4-row reads 4-8-way conflicted since
// (4*tx+rb)&31 takes only 8 values; (4*tx+rb)>>2 == tx spans all 32 banks].
// Row i = 64 h2: [word0 of quads 0..31][word1 of quads 0..31], quad q stored
// at slot q ^ (i>>2). Every access class -> <=2 lanes/bank (free, m136).
// Structure = R10's (unroll-1 chunk loops, VGPR 180, no spill) + merged
// final s5 RMW (one round instead of two).

__device__ __forceinline__ float ldshw(const h2* L, int i, int j) {
  int q = ((j >> 2) & 31) ^ (i >> 2);
  h2 p = L[(i << 6) + ((j & 2) << 4) + q];
  return (j & 1) ? (float)p.y : (float)p.x;
}

#define RDQ(L, I, B, M) {                                                      \
  int q_ = (B) ^ ((I) >> 2);                                                   \
  h2 p0_ = (L)[((I) << 6) + q_];                                               \
  h2 p1_ = (L)[((I) << 6) + 32 + q_];                                          \
  M.x = (float)p0_.x; M.y = (float)p0_.y;                                      \
  M.z = (float)p1_.x; M.w = (float)p1_.y; }

#define WRQ(L, I, B, V) {                                                      \
  int q_ = (B) ^ ((I) >> 2);                                                   \
  h2 p0_, p1_;                                                                 \
  p0_.x = (_Float16)V.x; p0_.y = (_Float16)V.y;                                \
  p1_.x = (_Float16)V.z; p1_.y = (_Float16)V.w;                                \
  (L)[((I) << 6) + q_] = p0_;                                                  \
  (L)[((I) << 6) + 32 + q_] = p1_; }

#define HROW(h, m, lo, hi)                                                     \
  h.x = lo + m.x + m.y; h.y = m.x + m.y + m.z;                                 \
  h.z = m.y + m.z + m.w; h.w = m.z + m.w + hi;

#define FMA4(T, C, M)                                                          \
  T.x += (C) * M.x; T.y += (C) * M.y; T.z += (C) * M.z; T.w += (C) * M.w;

#define BLUR4(T, A, B, Cq)                                                     \
  T.x += c1 * (A.x + B.x + Cq.x); T.y += c1 * (A.y + B.y + Cq.y);              \
  T.z += c1 * (A.z + B.z + Cq.z); T.w += c1 * (A.w + B.w + Cq.w);

#define FLIPL(T, M)                                                            \
  T.x += c2 * M.w; T.y += c2 * M.z; T.z += c2 * M.y; T.w += c2 * M.x;

#define GATHER(L, OI, TYC) {                                                   \
  float4 m, hA, hB, hC; float lo, hi; int ri;                                  \
  ri = ((OI) == 0) ? 1 : (OI) - 1;                                             \
  RDQ(L, ri, tx, m) lo = ldshw(L, ri, cLo); hi = ldshw(L, ri, cHi);            \
  HROW(hA, m, lo, hi)                                                          \
  RDQ(L, (OI), tx, m) lo = ldshw(L, (OI), cLo); hi = ldshw(L, (OI), cHi);      \
  FMA4(T0, c0, m)                                                              \
  HROW(hB, m, lo, hi)                                                          \
  RDQ(L, (OI)+1, tx, m) lo = ldshw(L, (OI)+1, cLo); hi = ldshw(L, (OI)+1, cHi);\
  FMA4(T1, c0, m)                                                              \
  HROW(hC, m, lo, hi)                                                          \
  BLUR4(T0, hA, hB, hC)                                                        \
  RDQ(L, (OI)+2, tx, m) lo = ldshw(L, (OI)+2, cLo); hi = ldshw(L, (OI)+2, cHi);\
  FMA4(T1, 0.0f, m) /* keep shape */                                           \
  FMA4(T2, c0, m)                                                              \
  HROW(hA, m, lo, hi)                                                          \
  BLUR4(T1, hB, hC, hA)                                                        \
  RDQ(L, (OI)+3, tx, m) lo = ldshw(L, (OI)+3, cLo); hi = ldshw(L, (OI)+3, cHi);\
  FMA4(T3, c0, m)                                                              \
  HROW(hB, m, lo, hi)                                                          \
  BLUR4(T2, hC, hA, hB)                                                        \
  ri = ((OI) == 124) ? 126 : (OI) + 4;                                         \
  RDQ(L, ri, tx, m) lo = ldshw(L, ri, cLo); hi = ldshw(L, ri, cHi);            \
  HROW(hC, m, lo, hi)                                                          \
  BLUR4(T3, hA, hB, hC)                                                        \
  /* fliplr */                                                                 \
  RDQ(L, (OI),   31 - tx, m) FLIPL(T0, m)                                      \
  RDQ(L, (OI)+1, 31 - tx, m) FLIPL(T1, m)                                      \
  RDQ(L, (OI)+2, 31 - tx, m) FLIPL(T2, m)                                      \
  RDQ(L, (OI)+3, 31 - tx, m) FLIPL(T3, m)                                      \
  /* flipud */                                                                 \
  RDQ(L, 127 - (OI), tx, m) FMA4(T0, c3, m)                                    \
  RDQ(L, 126 - (OI), tx, m) FMA4(T1, c3, m)                                    \
  RDQ(L, 125 - (OI), tx, m) FMA4(T2, c3, m)                                    \
  RDQ(L, 124 - (OI), tx, m) FMA4(T3, c3, m)                                    \
  /* roll(+4,+4) */                                                            \
  RDQ(L, ((OI) - 4) & 127, rc, m) FMA4(T0, c4, m)                              \
  RDQ(L, ((OI) - 3) & 127, rc, m) FMA4(T1, c4, m)                              \
  RDQ(L, ((OI) - 2) & 127, rc, m) FMA4(T2, c4, m)                              \
  RDQ(L, ((OI) - 1) & 127, rc, m) FMA4(T3, c4, m)                              \
  /* rot90 k=1: out[i][j] = src[j][127-i] */                                   \
  RDQ(L, oj,     31 - (TYC), m)                                                \
  T0.x += c5 * m.w; T1.x += c5 * m.z; T2.x += c5 * m.y; T3.x += c5 * m.x;      \
  RDQ(L, oj + 1, 31 - (TYC), m)                                                \
  T0.y += c5 * m.w; T1.y += c5 * m.z; T2.y += c5 * m.y; T3.y += c5 * m.x;      \
  RDQ(L, oj + 2, 31 - (TYC), m)                                                \
  T0.z += c5 * m.w; T1.z += c5 * m.z; T2.z += c5 * m.y; T3.z += c5 * m.x;      \
  RDQ(L, oj + 3, 31 - (TYC), m)                                                \
  T0.w += c5 * m.w; T1.w += c5 * m.z; T2.w += c5 * m.y; T3.w += c5 * m.x;      \
}

#define LDCF(P, TG) {                                                          \
  const float* cfp = wsf + WS_TAB + ((P) * 4 + (TG)) * 6;                      \
  c0 = cfp[0]; c1 = cfp[1]; c2 = cfp[2]; c3 = cfp[3]; c4 = cfp[4]; c5 = cfp[5]; }

#define SETC(K) {                                                              \
  float cst = wsf[WS_CONST + (K)];                                             \
  T0.x = cst; T0.y = cst; T0.z = cst; T0.w = cst; T1 = T0; T2 = T0; T3 = T0; }

#define STAGE_BN(L, OI) {                                                      \
  float4 v;                                                                    \
  v = x4[((OI)+0)*32 + tx]; v.x = v.x*sc+sh; v.y = v.y*sc+sh; v.z = v.z*sc+sh; \
  v.w = v.w*sc+sh; WRQ(L, (OI)+0, tx, v)                                       \
  v = x4[((OI)+1)*32 + tx]; v.x = v.x*sc+sh; v.y = v.y*sc+sh; v.z = v.z*sc+sh; \
  v.w = v.w*sc+sh; WRQ(L, (OI)+1, tx, v)                                       \
  v = x4[((OI)+2)*32 + tx]; v.x = v.x*sc+sh; v.y = v.y*sc+sh; v.z = v.z*sc+sh; \
  v.w = v.w*sc+sh; WRQ(L, (OI)+2, tx, v)                                       \
  v = x4[((OI)+3)*32 + tx]; v.x = v.x*sc+sh; v.y = v.y*sc+sh; v.z = v.z*sc+sh; \
  v.w = v.w*sc+sh; WRQ(L, (OI)+3, tx, v) }

#define STAGE_OUT(L, TG, OI) {                                                 \
  float4 v;                                                                    \
  v = out4[(pbase + (TG)*NCH)*4096 + ((OI)+0)*32 + tx]; WRQ(L, (OI)+0, tx, v)  \
  v = out4[(pbase + (TG)*NCH)*4096 + ((OI)+1)*32 + tx]; WRQ(L, (OI)+1, tx, v)  \
  v = out4[(pbase + (TG)*NCH)*4096 + ((OI)+2)*32 + tx]; WRQ(L, (OI)+2, tx, v)  \
  v = out4[(pbase + (TG)*NCH)*4096 + ((OI)+3)*32 + tx]; WRQ(L, (OI)+3, tx, v) }

#define WRITEV(TG, OI) {                                                       \
  out4[(pbase + (TG)*NCH)*4096 + ((OI)+0)*32 + tx] = T0;                       \
  out4[(pbase + (TG)*NCH)*4096 + ((OI)+1)*32 + tx] = T1;                       \
  out4[(pbase + (TG)*NCH)*4096 + ((OI)+2)*32 + tx] = T2;                       \
  out4[(pbase + (TG)*NCH)*4096 + ((OI)+3)*32 + tx] = T3; }

#define LOADV(TG, OI) {                                                        \
  T0 = out4[(pbase + (TG)*NCH)*4096 + ((OI)+0)*32 + tx];                       \
  T1 = out4[(pbase + (TG)*NCH)*4096 + ((OI)+1)*32 + tx];                       \
  T2 = out4[(pbase + (TG)*NCH)*4096 + ((OI)+2)*32 + tx];                       \
  T3 = out4[(pbase + (TG)*NCH)*4096 + ((OI)+3)*32 + tx]; }

#define STASHV(L, OI) {                                                        \
  WRQ(L, (OI)+0, tx, T0) WRQ(L, (OI)+1, tx, T1)                                \
  WRQ(L, (OI)+2, tx, T2) WRQ(L, (OI)+3, tx, T3) }

__global__ __launch_bounds__(256, 1)
void main_kernel(const float* __restrict__ x,
                 const float* __restrict__ wsf, float* out)
{
  __shared__ h2 lds[2 * 8192];            // 64 KB total -> 2 blocks/CU
  h2* h0 = lds;
  h2* h1 = lds + 8192;
  int bx = blockIdx.x;
  int b = bx / NCH, c = bx % NCH;
  int tid = threadIdx.x;
  int ty = tid >> 5, tx = tid & 31;       // ty in 0..7
  int oj = tx << 2;
  int cLo = (tx == 0)  ? 1   : oj - 1;
  int cHi = (tx == 31) ? 126 : oj + 4;
  int rc  = (tx + 31) & 31;
  float4* out4 = (float4*)out;
  const size_t pbase = (size_t)b * 192 + c;
  const float4* x4 = (const float4*)x + (size_t)bx * 4096;
  float sc = wsf[WS_SCALE + c], sh = wsf[WS_SHIFT + c];

  float4 T0, T1, T2, T3;
  float c0, c1, c2, c3, c4, c5;

  // stage s -> buf0
  #pragma unroll 1
  for (int k = 0; k < 4; ++k) {
    int oi = (ty + 8 * k) << 2;
    STAGE_BN(h0, oi);
  }
  __syncthreads();

  // s2 = L(0,0)[s]; stash s2 -> buf1
  #pragma unroll 1
  for (int k = 0; k < 4; ++k) {
    int oi = (ty + 8 * k) << 2; int tyc = ty + 8 * k;
    SETC(0); LDCF(0, 0);
    GATHER(h0, oi, tyc);
    WRITEV(0, oi);
    STASHV(h1, oi);
  }
  __syncthreads();

  // s3 full; s4,s5 partial contributions from s and s2
  #pragma unroll 1
  for (int k = 0; k < 4; ++k) {
    int oi = (ty + 8 * k) << 2; int tyc = ty + 8 * k;
    SETC(1); LDCF(0, 1); GATHER(h0, oi, tyc);
             LDCF(1, 1); GATHER(h1, oi, tyc);
    WRITEV(1, oi);
    SETC(2); LDCF(0, 2); GATHER(h0, oi, tyc);
             LDCF(1, 2); GATHER(h1, oi, tyc);
    WRITEV(2, oi);                          // partial s4
    SETC(3); LDCF(0, 3); GATHER(h0, oi, tyc);
             LDCF(1, 3); GATHER(h1, oi, tyc);
    WRITEV(3, oi);                          // partial s5
  }
  __syncthreads();                          // all buf0 reads done; s3 visible

  // restage s3 -> buf0
  #pragma unroll 1
  for (int k = 0; k < 4; ++k) {
    int oi = (ty + 8 * k) << 2;
    STAGE_OUT(h0, 1, oi);
  }
  __syncthreads();

  // s4 final (+= L(2,2)[s3]); stash s4 -> buf1 from regs (s2 reads all done)
  #pragma unroll 1
  for (int k = 0; k < 4; ++k) {
    int oi = (ty + 8 * k) << 2; int tyc = ty + 8 * k;
    LOADV(2, oi); LDCF(2, 2); GATHER(h0, oi, tyc); WRITEV(2, oi);
    STASHV(h1, oi);
  }
  __syncthreads();                          // s4 fully staged in buf1

  // s5 final: one RMW round, both remaining sources resident in LDS
  // (s3 in buf0, s4 in buf1) — merged from R10's two rounds
  #pragma unroll 1
  for (int k = 0; k < 4; ++k) {
    int oi = (ty + 8 * k) << 2; int tyc = ty + 8 * k;
    LOADV(3, oi);
    LDCF(2, 3); GATHER(h0, oi, tyc);
    LDCF(3, 3); GATHER(h1, oi, tyc);
    WRITEV(3, oi);
  }
}

extern "C" void kernel_launch(void* const* d_in, const int* in_sizes, int n_in,
                              void* d_out, int out_size, void* d_ws, size_t ws_size,
                              hipStream_t stream) {
  (void)in_sizes; (void)n_in; (void)out_size; (void)ws_size;
  const float* x     = (const float*)d_in[0];
  const float* gamma = (const float*)d_in[1];
  const float* beta  = (const float*)d_in[2];
  const float* a_red = (const float*)d_in[4];   // reference uses alphas_reduce
  float* ws  = (float*)d_ws;
  float* out = (float*)d_out;

  stats_kernel<<<NPLANES, 256, 0, stream>>>(x, ws);
  prep_kernel<<<1, 64, 0, stream>>>(gamma, beta, a_red, ws);
  main_kernel<<<NPLANES, 256, 0, stream>>>(x, ws, out);
}